// Round 5
// baseline (193.935 us; speedup 1.0000x reference)
//
#include <hip/hip_runtime.h>
#include <cstddef>

#define EPSF 1e-12f
#define NCB 90
#define NT 30
#define ODIM 256
#define DDIM 8192

typedef unsigned short u16;
typedef __attribute__((ext_vector_type(8))) short short8;
typedef __attribute__((ext_vector_type(4))) float float4v;

__device__ inline u16 f2bf(float f) {
  union { float f; unsigned u; } v; v.f = f;
  unsigned r = v.u + 0x7FFFu + ((v.u >> 16) & 1u);
  return (u16)(r >> 16);
}
__device__ inline float bf2f(u16 h) {
  union { unsigned u; float f; } v; v.u = ((unsigned)h) << 16;
  return v.f;
}

// ---------------------------------------------------------------------------
// K1 (MFMA): W hi/lo frags in REGISTERS (64 VGPR/wave), LDS 32.8 KB ->
// 3 blocks/CU. xf colblock stride 160 u16 (2-way write banks, free);
// xtf frag stride 520 u16 (4-way vs old 8-way).
// ---------------------------------------------------------------------------
__global__ __launch_bounds__(256, 3) void k1_assign(
    const float* __restrict__ x,       // [8][128][16][900]
    const float* __restrict__ conv_w,  // [64][128]
    const float* __restrict__ conv_b,  // [64]
    float* __restrict__ P,             // [8][90][64][128]
    float* __restrict__ PA)            // [8][90][64]
{
  __shared__ u16 xtf[4160];        // logits A-frags: F*520 + lane*8 + j
  __shared__ u16 xf[5120];         // P B-frags: ct*640 + (lane>>4)*160 + (lane&15)*8 + j
  __shared__ float As[64 * 33];    // logits -> exp
  __shared__ u16 afr[2048];        // a frags
  __shared__ float Mf[32];
  __shared__ float sm4[128];
  __shared__ float pasum[256];

  const int bx = blockIdx.x;
  const int n = bx / NCB, cb = bx - n * NCB;
  const int t = threadIdx.x;
  const int lane = t & 63;
  const int w = t >> 6;            // wave 0..3

  const float* xn = x + (size_t)n * 1843200 + cb * 10;

  const int colt = w & 1;
  const int kt0 = w >> 1;
  const float bk0 = conv_b[kt0 * 16 + (lane & 15)];
  const float bk1 = conv_b[(kt0 + 2) * 16 + (lane & 15)];

  // ---- W fragments (hi/lo split) in registers, loaded once per wave ----
  short8 w0h[4], w0l[4], w1h[4], w1l[4];
  {
    int kr0 = kt0 * 16 + (lane & 15);
    int kr1 = kr0 + 32;
    int cbase = (lane >> 4) << 3;
#pragma unroll
    for (int cb32 = 0; cb32 < 4; ++cb32) {
      const float* wp0 = conv_w + (size_t)kr0 * 128 + cb32 * 32 + cbase;
      const float* wp1 = conv_w + (size_t)kr1 * 128 + cb32 * 32 + cbase;
      union { u16 u[8]; short8 v; } hh, ll;
#pragma unroll
      for (int j = 0; j < 8; ++j) {
        float fv = wp0[j];
        u16 h = f2bf(fv);
        hh.u[j] = h;
        ll.u[j] = f2bf(fv - bf2f(h));
      }
      w0h[cb32] = hh.v; w0l[cb32] = ll.v;
#pragma unroll
      for (int j = 0; j < 8; ++j) {
        float fv = wp1[j];
        u16 h = f2bf(fv);
        hh.u[j] = h;
        ll.u[j] = f2bf(fv - bf2f(h));
      }
      w1h[cb32] = hh.v; w1l[cb32] = ll.v;
    }
  }

  float4v pacc[8];
#pragma unroll
  for (int i = 0; i < 8; ++i) pacc[i] = (float4v){0.f, 0.f, 0.f, 0.f};
  float pak = 0.f;

  for (int cc = 0; cc < 5; ++cc) {
    __syncthreads();  // protect xf/xtf/afr reuse across cc
    // ---- stage X: float2 reads (pairs never cross 10-runs), 2 LDS layouts ----
#pragma unroll
    for (int s = 0; s < 8; ++s) {
      int e2 = t + 256 * s;
      int c = e2 >> 4, p = e2 & 15;
      int cl = 2 * p;
      int g = cc * 32 + cl;
      int h = g / 10, wi = g - 10 * h;
      float2 val = *(const float2*)(xn + (size_t)c * 14400 + h * 900 + wi);
      u16 h0 = f2bf(val.x), h1 = f2bf(val.y);
      // P layout (stride-160 colblocks): one 4B store, 2-way banks
      int ip = (c >> 4) * 640 + (p >> 2) * 160 + (c & 15) * 8 + (cl & 7);
      ushort2 pr; pr.x = h0; pr.y = h1;
      *(ushort2*)&xf[ip] = pr;
      // logits layout (frag stride 520): two 2B stores, 4-way banks
      int F = (p >> 3) * 4 + (c >> 5);
      int L = (((c >> 3) & 3) << 4) + (cl & 15);
      int i0 = F * 520 + L * 8 + (c & 7);
      xtf[i0] = h0;
      xtf[i0 + 8] = h1;
    }
    __syncthreads();

    // ---- logits MFMA: L^T = X^T @ (Wh + Wl), W from registers ----
    {
      float4v d0 = (float4v){0.f, 0.f, 0.f, 0.f};
      float4v d1 = (float4v){0.f, 0.f, 0.f, 0.f};
#pragma unroll
      for (int cb32 = 0; cb32 < 4; ++cb32) {
        short8 xa = *(short8*)&xtf[(colt * 4 + cb32) * 520 + lane * 8];
        d0 = __builtin_amdgcn_mfma_f32_16x16x32_bf16(xa, w0h[cb32], d0, 0, 0, 0);
        d0 = __builtin_amdgcn_mfma_f32_16x16x32_bf16(xa, w0l[cb32], d0, 0, 0, 0);
        d1 = __builtin_amdgcn_mfma_f32_16x16x32_bf16(xa, w1h[cb32], d1, 0, 0, 0);
        d1 = __builtin_amdgcn_mfma_f32_16x16x32_bf16(xa, w1l[cb32], d1, 0, 0, 0);
      }
      int colb = colt * 16 + ((lane >> 4) << 2);
      int kr0 = kt0 * 16 + (lane & 15);
      int kr1 = kr0 + 32;
#pragma unroll
      for (int r = 0; r < 4; ++r) {
        As[kr0 * 33 + colb + r] = d0[r] + bk0;
        As[kr1 * 33 + colb + r] = d1[r] + bk1;
      }
    }
    __syncthreads();

    // ---- softmax over k per column ----
    if (t < 32) {
      float m = -3.4e38f;
#pragma unroll
      for (int kk = 0; kk < 64; ++kk) m = fmaxf(m, As[kk * 33 + t]);
      Mf[t] = m;
    }
    __syncthreads();
    if (t < 128) {
      int col = t & 31, kg = t >> 5;
      float M = Mf[col], s = 0.f;
#pragma unroll
      for (int ii = 0; ii < 16; ++ii) {
        int a = (kg * 16 + ii) * 33 + col;
        float e = __expf(As[a] - M);
        As[a] = e;
        s += e;
      }
      sm4[kg * 32 + col] = s;
    }
    __syncthreads();

    // ---- build a-fragments (bf16) + PA partial ----
    {
      int k = t & 63, cg = t >> 6;
      union { u16 u[8]; short8 v; } cvt;
      float paks = 0.f;
#pragma unroll
      for (int j = 0; j < 8; ++j) {
        int col = cg * 8 + j;
        float inv = 1.f / (sm4[col] + sm4[32 + col] + sm4[64 + col] + sm4[96 + col]);
        float a = As[k * 33 + col] * inv;
        paks += a;
        cvt.u[j] = f2bf(a);
      }
      pak += paks;
      int dst = ((k >> 4) * 64 + (cg << 4) + (k & 15)) * 8;
      *(short8*)&afr[dst] = cvt.v;
    }
    __syncthreads();

    // ---- P MFMA: wave w owns kt = w; 8 c-tiles ----
    {
      short8 aa = *(short8*)&afr[(w * 64 + lane) * 8];
#pragma unroll
      for (int ct = 0; ct < 8; ++ct) {
        short8 xb = *(short8*)&xf[ct * 640 + (lane >> 4) * 160 + (lane & 15) * 8];
        pacc[ct] = __builtin_amdgcn_mfma_f32_16x16x32_bf16(aa, xb, pacc[ct], 0, 0, 0);
      }
    }
  }

  float* Pp = P + (size_t)(n * NCB + cb) * DDIM;
  {
    int krow = w * 16 + ((lane >> 4) << 2);
    int c0 = lane & 15;
#pragma unroll
    for (int ct = 0; ct < 8; ++ct)
#pragma unroll
      for (int r = 0; r < 4; ++r)
        Pp[(krow + r) * 128 + ct * 16 + c0] = pacc[ct][r];
  }
  pasum[t] = pak;
  __syncthreads();
  if (t < 64)
    PA[(size_t)(n * NCB + cb) * 64 + t] =
        pasum[t] + pasum[64 + t] + pasum[128 + t] + pasum[192 + t];
}

// ---------------------------------------------------------------------------
// K2a: in-place inclusive cumsum over the 90-chunk axis of P (and PA).
// Blocks 0..255: P (thread = one (n,e)); blocks 256..257: PA.
// ---------------------------------------------------------------------------
__global__ __launch_bounds__(256) void k2a_cumsum(
    float* __restrict__ P, float* __restrict__ PA)
{
  const int b = blockIdx.x;
  const int t = threadIdx.x;
  if (b < 256) {
    const int n = b >> 5;
    const int e = ((b & 31) << 8) + t;
    float* p = P + (size_t)n * NCB * DDIM + e;
    float acc = 0.f;
#pragma unroll 6
    for (int i = 0; i < NCB; ++i) {
      float v = p[(size_t)i * DDIM];
      acc += v;
      p[(size_t)i * DDIM] = acc;
    }
  } else {
    const int idx = ((b - 256) << 8) + t;   // 0..511
    const int n = idx >> 6, k = idx & 63;
    float* p = PA + (size_t)n * NCB * 64 + k;
    float acc = 0.f;
#pragma unroll 6
    for (int i = 0; i < NCB; ++i) {
      float v = p[(size_t)i * 64];
      acc += v;
      p[(size_t)i * 64] = acc;
    }
  }
}

// ---------------------------------------------------------------------------
// K2b: window = prefix-slice differences (2-3 slices vs 20 chunk reads),
// residual, intra-norm; per-eb global-ss -> gss.
// ---------------------------------------------------------------------------
__global__ __launch_bounds__(256) void k2b_vlad(
    const float* __restrict__ P, const float* __restrict__ PA,
    const float* __restrict__ centers, float* __restrict__ vlad,
    float* __restrict__ gss)
{
  __shared__ float Ak[16];
  __shared__ float red[4];
  const int b = blockIdx.x;
  const int win = b >> 2, eb = b & 3;
  const int n = win / NT, wt = win - n * NT;
  const int t = threadIdx.x;

  const int a = (3 * wt + 80) % 90;        // a >= 1 always (a == 2 mod 3)
  const int bidx = a + 20;                 // never exactly 90
  const bool wrap = bidx > 90;
  const int i0 = a - 1;
  const int i1 = wrap ? 89 : bidx - 1;
  const int i2 = wrap ? bidx - 91 : 0;     // valid only if wrap

  if (t < 16) {
    int k = eb * 16 + t;
    const float* pa = PA + (size_t)n * NCB * 64 + k;
    float s = pa[(size_t)i1 * 64] - pa[(size_t)i0 * 64];
    if (wrap) s += pa[(size_t)i2 * 64];
    Ak[t] = s;
  }
  __syncthreads();

  const int e0 = eb * 2048 + t * 8;
  const float* base = P + (size_t)n * NCB * DDIM + e0;
  const float* R0 = base + (size_t)i0 * DDIM;
  const float* R1 = base + (size_t)i1 * DDIM;
  const float* R2 = base + (size_t)i2 * DDIM;
  float v[8];
  {
    float4 a0 = *(const float4*)R1, a1 = *(const float4*)(R1 + 4);
    float4 b0 = *(const float4*)R0, b1 = *(const float4*)(R0 + 4);
    v[0] = a0.x - b0.x; v[1] = a0.y - b0.y; v[2] = a0.z - b0.z; v[3] = a0.w - b0.w;
    v[4] = a1.x - b1.x; v[5] = a1.y - b1.y; v[6] = a1.z - b1.z; v[7] = a1.w - b1.w;
    if (wrap) {
      float4 c0 = *(const float4*)R2, c1 = *(const float4*)(R2 + 4);
      v[0] += c0.x; v[1] += c0.y; v[2] += c0.z; v[3] += c0.w;
      v[4] += c1.x; v[5] += c1.y; v[6] += c1.z; v[7] += c1.w;
    }
  }
  const float A = Ak[t >> 4];
  const float* ce = centers + e0;
  float ss8 = 0.f;
#pragma unroll
  for (int j = 0; j < 8; ++j) {
    float val = v[j] - ce[j] * A;
    v[j] = val;
    ss8 += val * val;
  }
  float ssg = ss8;
  ssg += __shfl_xor(ssg, 1);
  ssg += __shfl_xor(ssg, 2);
  ssg += __shfl_xor(ssg, 4);
  ssg += __shfl_xor(ssg, 8);
  float rn = 1.f / fmaxf(sqrtf(ssg), EPSF);
#pragma unroll
  for (int j = 0; j < 8; ++j) v[j] *= rn;
  float ts = ss8 * rn * rn;
  ts += __shfl_xor(ts, 1);
  ts += __shfl_xor(ts, 2);
  ts += __shfl_xor(ts, 4);
  ts += __shfl_xor(ts, 8);
  ts += __shfl_xor(ts, 16);
  ts += __shfl_xor(ts, 32);
  if ((t & 63) == 0) red[t >> 6] = ts;
  __syncthreads();
  if (t == 0) gss[(size_t)win * 4 + eb] = red[0] + red[1] + red[2] + red[3];

  float* vp = vlad + (size_t)win * DDIM + e0;
  *(float4*)vp = make_float4(v[0], v[1], v[2], v[3]);
  *(float4*)(vp + 4) = make_float4(v[4], v[5], v[6], v[7]);
}

// ---------------------------------------------------------------------------
// K3: part = (g .* vlad)(240x8192) @ mlp_w^T, split-K x16, tile 16r x 128o
// ---------------------------------------------------------------------------
__global__ __launch_bounds__(256) void k3_gemm(
    const float* __restrict__ vlad, const float* __restrict__ gss,
    const float* __restrict__ mlp_w, float* __restrict__ part)  // [16][240][256]
{
  __shared__ float va[16 * 68];
  __shared__ float wbt[64 * 129];
  __shared__ float ga[16];
  const int bx = blockIdx.x;
  const int rt = bx % 15;
  const int hx = bx / 15;
  const int ot = hx & 1, ks = hx >> 1;
  const int t = threadIdx.x;

  if (t < 16) {
    int r = rt * 16 + t;
    float s = gss[r * 4] + gss[r * 4 + 1] + gss[r * 4 + 2] + gss[r * 4 + 3];
    ga[t] = 1.f / fmaxf(sqrtf(s), EPSF);
  }

  const int rr = (t >> 5) << 1;
  const int o0 = t & 31;
  float acc[2][4];
#pragma unroll
  for (int a = 0; a < 2; ++a)
#pragma unroll
    for (int u = 0; u < 4; ++u) acc[a][u] = 0.f;

  const int d0 = ks * 512;
  for (int dc = 0; dc < 512; dc += 64) {
    __syncthreads();
    {
      int r = t >> 4, dq = t & 15;
      float4 u = *(const float4*)(vlad + (size_t)(rt * 16 + r) * DDIM + d0 + dc + 4 * dq);
      float g = ga[r];
      u.x *= g; u.y *= g; u.z *= g; u.w *= g;
      *(float4*)&va[r * 68 + 4 * dq] = u;
    }
#pragma unroll
    for (int s = 0; s < 8; ++s) {
      int f = t + 256 * s;
      int o = f >> 4, dq = f & 15;
      float4 u = *(const float4*)(mlp_w + (size_t)(ot * 128 + o) * DDIM + d0 + dc + 4 * dq);
      wbt[(4 * dq + 0) * 129 + o] = u.x;
      wbt[(4 * dq + 1) * 129 + o] = u.y;
      wbt[(4 * dq + 2) * 129 + o] = u.z;
      wbt[(4 * dq + 3) * 129 + o] = u.w;
    }
    __syncthreads();
#pragma unroll 8
    for (int dd = 0; dd < 64; ++dd) {
      float x0 = va[rr * 68 + dd];
      float x1 = va[(rr + 1) * 68 + dd];
      float y0 = wbt[dd * 129 + o0];
      float y1 = wbt[dd * 129 + o0 + 32];
      float y2 = wbt[dd * 129 + o0 + 64];
      float y3 = wbt[dd * 129 + o0 + 96];
      acc[0][0] += x0 * y0; acc[0][1] += x0 * y1; acc[0][2] += x0 * y2; acc[0][3] += x0 * y3;
      acc[1][0] += x1 * y0; acc[1][1] += x1 * y1; acc[1][2] += x1 * y2; acc[1][3] += x1 * y3;
    }
  }
  float* pp = part + ((size_t)ks * 240 + rt * 16) * ODIM + ot * 128;
#pragma unroll
  for (int a = 0; a < 2; ++a)
#pragma unroll
    for (int u = 0; u < 4; ++u)
      pp[(rr + a) * ODIM + o0 + 32 * u] = acc[a][u];
}

// ---------------------------------------------------------------------------
// K4: sum split-K partials + bias, row-normalize 240 x 256
// ---------------------------------------------------------------------------
__global__ __launch_bounds__(256) void k4_out(
    const float* __restrict__ part, const float* __restrict__ bias,
    float* __restrict__ out)
{
  __shared__ float red[4];
  const int r = blockIdx.x;
  const int o = threadIdx.x;
  float v = bias[o];
#pragma unroll
  for (int s = 0; s < 16; ++s) v += part[((size_t)s * 240 + r) * ODIM + o];
  float ss = v * v;
  ss += __shfl_xor(ss, 32);
  ss += __shfl_xor(ss, 16);
  ss += __shfl_xor(ss, 8);
  ss += __shfl_xor(ss, 4);
  ss += __shfl_xor(ss, 2);
  ss += __shfl_xor(ss, 1);
  if ((o & 63) == 0) red[o >> 6] = ss;
  __syncthreads();
  float total = red[0] + red[1] + red[2] + red[3];
  out[(size_t)r * ODIM + o] = v / fmaxf(sqrtf(total), EPSF);
}

// ---------------------------------------------------------------------------
extern "C" void kernel_launch(void* const* d_in, const int* in_sizes, int n_in,
                              void* d_out, int out_size, void* d_ws, size_t ws_size,
                              hipStream_t stream) {
  const float* x       = (const float*)d_in[0];
  const float* centers = (const float*)d_in[1];
  const float* conv_w  = (const float*)d_in[2];
  const float* conv_b  = (const float*)d_in[3];
  const float* mlp_w   = (const float*)d_in[4];
  const float* mlp_b   = (const float*)d_in[5];
  float* out = (float*)d_out;

  float* ws   = (float*)d_ws;
  float* P    = ws;                       // 8*90*64*128 = 5,898,240 floats
  float* PA   = P + (size_t)5898240;      // 46,080
  float* vlad = PA + (size_t)46080;       // 240*8192 = 1,966,080
  float* gss  = vlad + (size_t)1966080;   // 960
  float* part = ws;                       // [16][240][256] overlays P (dead after k2b)

  k1_assign<<<dim3(8 * NCB), dim3(256), 0, stream>>>(x, conv_w, conv_b, P, PA);
  k2a_cumsum<<<dim3(258), dim3(256), 0, stream>>>(P, PA);
  k2b_vlad <<<dim3(8 * NT * 4), dim3(256), 0, stream>>>(P, PA, centers, vlad, gss);
  k3_gemm  <<<dim3(480), dim3(256), 0, stream>>>(vlad, gss, mlp_w, part);
  k4_out   <<<dim3(240), dim3(256), 0, stream>>>(part, mlp_b, out);
}

// Round 6
// 174.123 us; speedup vs baseline: 1.1138x; 1.1138x over previous
//
#include <hip/hip_runtime.h>
#include <cstddef>

#define EPSF 1e-12f
#define NCB 90
#define NT 30
#define ODIM 256
#define DDIM 8192

typedef unsigned short u16;
typedef __attribute__((ext_vector_type(8))) short short8;
typedef __attribute__((ext_vector_type(4))) float float4v;

__device__ inline u16 f2bf(float f) {
  union { float f; unsigned u; } v; v.f = f;
  unsigned r = v.u + 0x7FFFu + ((v.u >> 16) & 1u);
  return (u16)(r >> 16);
}
__device__ inline float bf2f(u16 h) {
  union { unsigned u; float f; } v; v.u = ((unsigned)h) << 16;
  return v.f;
}

// ---------------------------------------------------------------------------
// K0: convert mlp_w (256x8192 fp32) -> bf16, 8 elems/thread
// ---------------------------------------------------------------------------
__global__ __launch_bounds__(256) void k0_conv(
    const float* __restrict__ w, u16* __restrict__ w16)
{
  int i = (blockIdx.x * 256 + threadIdx.x) * 8;
  float4 a = *(const float4*)(w + i);
  float4 b = *(const float4*)(w + i + 4);
  union { u16 u[8]; short8 v; } o;
  o.u[0] = f2bf(a.x); o.u[1] = f2bf(a.y); o.u[2] = f2bf(a.z); o.u[3] = f2bf(a.w);
  o.u[4] = f2bf(b.x); o.u[5] = f2bf(b.y); o.u[6] = f2bf(b.z); o.u[7] = f2bf(b.w);
  *(short8*)(w16 + i) = o.v;
}

// ---------------------------------------------------------------------------
// K1 (MFMA): identical to R5 (60 µs). W hi/lo frags in registers, LDS 32.8 KB.
// ---------------------------------------------------------------------------
__global__ __launch_bounds__(256, 3) void k1_assign(
    const float* __restrict__ x,       // [8][128][16][900]
    const float* __restrict__ conv_w,  // [64][128]
    const float* __restrict__ conv_b,  // [64]
    float* __restrict__ P,             // [8][90][64][128]
    float* __restrict__ PA)            // [8][90][64]
{
  __shared__ u16 xtf[4160];        // logits A-frags: F*520 + lane*8 + j
  __shared__ u16 xf[5120];         // P B-frags: ct*640 + (lane>>4)*160 + (lane&15)*8 + j
  __shared__ float As[64 * 33];    // logits -> exp
  __shared__ u16 afr[2048];        // a frags
  __shared__ float Mf[32];
  __shared__ float sm4[128];
  __shared__ float pasum[256];

  const int bx = blockIdx.x;
  const int n = bx / NCB, cb = bx - n * NCB;
  const int t = threadIdx.x;
  const int lane = t & 63;
  const int w = t >> 6;            // wave 0..3

  const float* xn = x + (size_t)n * 1843200 + cb * 10;

  const int colt = w & 1;
  const int kt0 = w >> 1;
  const float bk0 = conv_b[kt0 * 16 + (lane & 15)];
  const float bk1 = conv_b[(kt0 + 2) * 16 + (lane & 15)];

  short8 w0h[4], w0l[4], w1h[4], w1l[4];
  {
    int kr0 = kt0 * 16 + (lane & 15);
    int kr1 = kr0 + 32;
    int cbase = (lane >> 4) << 3;
#pragma unroll
    for (int cb32 = 0; cb32 < 4; ++cb32) {
      const float* wp0 = conv_w + (size_t)kr0 * 128 + cb32 * 32 + cbase;
      const float* wp1 = conv_w + (size_t)kr1 * 128 + cb32 * 32 + cbase;
      union { u16 u[8]; short8 v; } hh, ll;
#pragma unroll
      for (int j = 0; j < 8; ++j) {
        float fv = wp0[j];
        u16 h = f2bf(fv);
        hh.u[j] = h;
        ll.u[j] = f2bf(fv - bf2f(h));
      }
      w0h[cb32] = hh.v; w0l[cb32] = ll.v;
#pragma unroll
      for (int j = 0; j < 8; ++j) {
        float fv = wp1[j];
        u16 h = f2bf(fv);
        hh.u[j] = h;
        ll.u[j] = f2bf(fv - bf2f(h));
      }
      w1h[cb32] = hh.v; w1l[cb32] = ll.v;
    }
  }

  float4v pacc[8];
#pragma unroll
  for (int i = 0; i < 8; ++i) pacc[i] = (float4v){0.f, 0.f, 0.f, 0.f};
  float pak = 0.f;

  for (int cc = 0; cc < 5; ++cc) {
    __syncthreads();
#pragma unroll
    for (int s = 0; s < 8; ++s) {
      int e2 = t + 256 * s;
      int c = e2 >> 4, p = e2 & 15;
      int cl = 2 * p;
      int g = cc * 32 + cl;
      int h = g / 10, wi = g - 10 * h;
      float2 val = *(const float2*)(xn + (size_t)c * 14400 + h * 900 + wi);
      u16 h0 = f2bf(val.x), h1 = f2bf(val.y);
      int ip = (c >> 4) * 640 + (p >> 2) * 160 + (c & 15) * 8 + (cl & 7);
      ushort2 pr; pr.x = h0; pr.y = h1;
      *(ushort2*)&xf[ip] = pr;
      int F = (p >> 3) * 4 + (c >> 5);
      int L = (((c >> 3) & 3) << 4) + (cl & 15);
      int i0 = F * 520 + L * 8 + (c & 7);
      xtf[i0] = h0;
      xtf[i0 + 8] = h1;
    }
    __syncthreads();

    {
      float4v d0 = (float4v){0.f, 0.f, 0.f, 0.f};
      float4v d1 = (float4v){0.f, 0.f, 0.f, 0.f};
#pragma unroll
      for (int cb32 = 0; cb32 < 4; ++cb32) {
        short8 xa = *(short8*)&xtf[(colt * 4 + cb32) * 520 + lane * 8];
        d0 = __builtin_amdgcn_mfma_f32_16x16x32_bf16(xa, w0h[cb32], d0, 0, 0, 0);
        d0 = __builtin_amdgcn_mfma_f32_16x16x32_bf16(xa, w0l[cb32], d0, 0, 0, 0);
        d1 = __builtin_amdgcn_mfma_f32_16x16x32_bf16(xa, w1h[cb32], d1, 0, 0, 0);
        d1 = __builtin_amdgcn_mfma_f32_16x16x32_bf16(xa, w1l[cb32], d1, 0, 0, 0);
      }
      int colb = colt * 16 + ((lane >> 4) << 2);
      int kr0 = kt0 * 16 + (lane & 15);
      int kr1 = kr0 + 32;
#pragma unroll
      for (int r = 0; r < 4; ++r) {
        As[kr0 * 33 + colb + r] = d0[r] + bk0;
        As[kr1 * 33 + colb + r] = d1[r] + bk1;
      }
    }
    __syncthreads();

    if (t < 32) {
      float m = -3.4e38f;
#pragma unroll
      for (int kk = 0; kk < 64; ++kk) m = fmaxf(m, As[kk * 33 + t]);
      Mf[t] = m;
    }
    __syncthreads();
    if (t < 128) {
      int col = t & 31, kg = t >> 5;
      float M = Mf[col], s = 0.f;
#pragma unroll
      for (int ii = 0; ii < 16; ++ii) {
        int a = (kg * 16 + ii) * 33 + col;
        float e = __expf(As[a] - M);
        As[a] = e;
        s += e;
      }
      sm4[kg * 32 + col] = s;
    }
    __syncthreads();

    {
      int k = t & 63, cg = t >> 6;
      union { u16 u[8]; short8 v; } cvt;
      float paks = 0.f;
#pragma unroll
      for (int j = 0; j < 8; ++j) {
        int col = cg * 8 + j;
        float inv = 1.f / (sm4[col] + sm4[32 + col] + sm4[64 + col] + sm4[96 + col]);
        float a = As[k * 33 + col] * inv;
        paks += a;
        cvt.u[j] = f2bf(a);
      }
      pak += paks;
      int dst = ((k >> 4) * 64 + (cg << 4) + (k & 15)) * 8;
      *(short8*)&afr[dst] = cvt.v;
    }
    __syncthreads();

    {
      short8 aa = *(short8*)&afr[(w * 64 + lane) * 8];
#pragma unroll
      for (int ct = 0; ct < 8; ++ct) {
        short8 xb = *(short8*)&xf[ct * 640 + (lane >> 4) * 160 + (lane & 15) * 8];
        pacc[ct] = __builtin_amdgcn_mfma_f32_16x16x32_bf16(aa, xb, pacc[ct], 0, 0, 0);
      }
    }
  }

  float* Pp = P + (size_t)(n * NCB + cb) * DDIM;
  {
    int krow = w * 16 + ((lane >> 4) << 2);
    int c0 = lane & 15;
#pragma unroll
    for (int ct = 0; ct < 8; ++ct)
#pragma unroll
      for (int r = 0; r < 4; ++r)
        Pp[(krow + r) * 128 + ct * 16 + c0] = pacc[ct][r];
  }
  pasum[t] = pak;
  __syncthreads();
  if (t < 64)
    PA[(size_t)(n * NCB + cb) * 64 + t] =
        pasum[t] + pasum[64 + t] + pasum[128 + t] + pasum[192 + t];
}

// ---------------------------------------------------------------------------
// K2: direct window sums (20 chunks, raw P), residual, intra-norm; writes
// vlad in BF16 (global scale deferred to K3 epilogue) + gss partials.
// ---------------------------------------------------------------------------
__global__ __launch_bounds__(256) void k2_vlad(
    const float* __restrict__ P, const float* __restrict__ PA,
    const float* __restrict__ centers, u16* __restrict__ vlad16,
    float* __restrict__ gss)
{
  __shared__ float Ak[16];
  __shared__ float red[4];
  const int b = blockIdx.x;
  const int win = b >> 2, eb = b & 3;
  const int n = win / NT, wt = win - n * NT;
  const int t = threadIdx.x;

  if (t < 64) {
    int kk = t >> 2, ii = t & 3;
    float s = 0.f;
#pragma unroll
    for (int ss = 0; ss < 5; ++ss) {
      int i = ii + 4 * ss;
      int cb = (3 * wt + 80 + i) % 90;
      s += PA[((size_t)n * NCB + cb) * 64 + eb * 16 + kk];
    }
    s += __shfl_xor(s, 1);
    s += __shfl_xor(s, 2);
    if (ii == 0) Ak[kk] = s;
  }
  __syncthreads();

  const int e0 = eb * 2048 + t * 8;
  float v[8];
#pragma unroll
  for (int j = 0; j < 8; ++j) v[j] = 0.f;
#pragma unroll 5
  for (int i = 0; i < 20; ++i) {
    int cb = (3 * wt + 80 + i) % 90;
    const float* Pp = P + ((size_t)n * NCB + cb) * DDIM + e0;
    float4 u0 = *(const float4*)Pp;
    float4 u1 = *(const float4*)(Pp + 4);
    v[0] += u0.x; v[1] += u0.y; v[2] += u0.z; v[3] += u0.w;
    v[4] += u1.x; v[5] += u1.y; v[6] += u1.z; v[7] += u1.w;
  }
  const float A = Ak[t >> 4];
  const float* ce = centers + e0;
  float ss8 = 0.f;
#pragma unroll
  for (int j = 0; j < 8; ++j) {
    float val = v[j] - ce[j] * A;
    v[j] = val;
    ss8 += val * val;
  }
  float ssg = ss8;
  ssg += __shfl_xor(ssg, 1);
  ssg += __shfl_xor(ssg, 2);
  ssg += __shfl_xor(ssg, 4);
  ssg += __shfl_xor(ssg, 8);
  float rn = 1.f / fmaxf(sqrtf(ssg), EPSF);
  float ts = ss8 * rn * rn;
  ts += __shfl_xor(ts, 1);
  ts += __shfl_xor(ts, 2);
  ts += __shfl_xor(ts, 4);
  ts += __shfl_xor(ts, 8);
  ts += __shfl_xor(ts, 16);
  ts += __shfl_xor(ts, 32);
  if ((t & 63) == 0) red[t >> 6] = ts;
  __syncthreads();
  if (t == 0) gss[(size_t)win * 4 + eb] = red[0] + red[1] + red[2] + red[3];

  union { u16 u[8]; short8 s; } o;
#pragma unroll
  for (int j = 0; j < 8; ++j) o.u[j] = f2bf(v[j] * rn);
  *(short8*)(vlad16 + (size_t)win * DDIM + e0) = o.s;
}

// ---------------------------------------------------------------------------
// K3 (MFMA): part[ks][240][256] = (vlad16 @ mlpw16^T) * ga[r].
// No LDS in K-loop: A/B fragments loaded directly from global (L2-hot).
// A-frag: lane reads vlad16[row=rt*16+(lane&15)][d0 + (lane>>4)*8 .. +8].
// B-frag: lane reads mlpw16[o][same d]. D: row=(lane>>4)*4+reg, col=lane&15.
// Grid: 15 rt x 32 ks. Wave w owns o in [64w, 64w+64): 4 n-tiles.
// ---------------------------------------------------------------------------
__global__ __launch_bounds__(256) void k3_gemm(
    const u16* __restrict__ vlad16, const float* __restrict__ gss,
    const u16* __restrict__ w16, float* __restrict__ part)
{
  __shared__ float ga[16];
  const int bx = blockIdx.x;
  const int rt = bx % 15;
  const int ks = bx / 15;          // 0..31, K-slice of 256
  const int t = threadIdx.x;
  const int lane = t & 63;
  const int w = t >> 6;

  if (t < 16) {
    int r = rt * 16 + t;
    float s = gss[r * 4] + gss[r * 4 + 1] + gss[r * 4 + 2] + gss[r * 4 + 3];
    ga[t] = 1.f / fmaxf(sqrtf(s), EPSF);
  }
  __syncthreads();

  const int m = lane & 15;
  const int kg = lane >> 4;
  const int d0 = ks * 256 + kg * 8;
  const u16* arow = vlad16 + (size_t)(rt * 16 + m) * DDIM + d0;

  float4v acc[4];
#pragma unroll
  for (int i = 0; i < 4; ++i) acc[i] = (float4v){0.f, 0.f, 0.f, 0.f};

#pragma unroll
  for (int ko = 0; ko < 8; ++ko) {
    short8 a = *(const short8*)(arow + ko * 32);
#pragma unroll
    for (int nt = 0; nt < 4; ++nt) {
      int o = w * 64 + nt * 16 + m;
      short8 b = *(const short8*)(w16 + (size_t)o * DDIM + d0 + ko * 32);
      acc[nt] = __builtin_amdgcn_mfma_f32_16x16x32_bf16(a, b, acc[nt], 0, 0, 0);
    }
  }

  float g4[4];
#pragma unroll
  for (int r = 0; r < 4; ++r) g4[r] = ga[kg * 4 + r];
  float* pp = part + ((size_t)ks * 240 + rt * 16) * ODIM;
#pragma unroll
  for (int nt = 0; nt < 4; ++nt) {
    int o = w * 64 + nt * 16 + m;
#pragma unroll
    for (int r = 0; r < 4; ++r)
      pp[(kg * 4 + r) * ODIM + o] = acc[nt][r] * g4[r];
  }
}

// ---------------------------------------------------------------------------
// K4: sum 32 split-K partials + bias, row-normalize 240 x 256
// ---------------------------------------------------------------------------
__global__ __launch_bounds__(256) void k4_out(
    const float* __restrict__ part, const float* __restrict__ bias,
    float* __restrict__ out)
{
  __shared__ float red[4];
  const int r = blockIdx.x;
  const int o = threadIdx.x;
  float v = bias[o];
#pragma unroll
  for (int s = 0; s < 32; ++s) v += part[((size_t)s * 240 + r) * ODIM + o];
  float ss = v * v;
  ss += __shfl_xor(ss, 32);
  ss += __shfl_xor(ss, 16);
  ss += __shfl_xor(ss, 8);
  ss += __shfl_xor(ss, 4);
  ss += __shfl_xor(ss, 2);
  ss += __shfl_xor(ss, 1);
  if ((o & 63) == 0) red[o >> 6] = ss;
  __syncthreads();
  float total = red[0] + red[1] + red[2] + red[3];
  out[(size_t)r * ODIM + o] = v / fmaxf(sqrtf(total), EPSF);
}

// ---------------------------------------------------------------------------
extern "C" void kernel_launch(void* const* d_in, const int* in_sizes, int n_in,
                              void* d_out, int out_size, void* d_ws, size_t ws_size,
                              hipStream_t stream) {
  const float* x       = (const float*)d_in[0];
  const float* centers = (const float*)d_in[1];
  const float* conv_w  = (const float*)d_in[2];
  const float* conv_b  = (const float*)d_in[3];
  const float* mlp_w   = (const float*)d_in[4];
  const float* mlp_b   = (const float*)d_in[5];
  float* out = (float*)d_out;

  float* ws     = (float*)d_ws;
  float* P      = ws;                              // 5,898,240 floats (23.6 MB)
  float* PA     = ws + 5898240;                    // 46,080 floats
  u16*   vlad16 = (u16*)(ws + 5944320);            // 240*8192 u16 (3.9 MB)
  float* gss    = (float*)((char*)d_ws + 27709440);// 960 floats
  u16*   mlpw16 = (u16*)((char*)d_ws + 27713280);  // 256*8192 u16 (4 MB) -> 30.4 MB total
  float* part   = ws;                              // [32][240][256] overlays dead P

  k0_conv  <<<dim3(1024),     dim3(256), 0, stream>>>(mlp_w, mlpw16);
  k1_assign<<<dim3(8 * NCB),  dim3(256), 0, stream>>>(x, conv_w, conv_b, P, PA);
  k2_vlad  <<<dim3(8 * NT * 4), dim3(256), 0, stream>>>(P, PA, centers, vlad16, gss);
  k3_gemm  <<<dim3(480),      dim3(256), 0, stream>>>(vlad16, gss, mlpw16, part);
  k4_out   <<<dim3(240),      dim3(256), 0, stream>>>(part, mlp_b, out);
}